// Round 18
// baseline (64.939 us; speedup 1.0000x reference)
//
#include <hip/hip_runtime.h>
#include <math.h>

#define BDIM 512
#define IDIM 256
#define ODIM 512

// 16B table entry: correctly-rounded fp64 reciprocal of den, comp, raw value.
struct __align__(16) XT { double r; float c; float raw; };

// jnp.minimum(q, 1.0): NaN-propagating min with 1.0 (slow/general path)
__device__ __forceinline__ float np_min1(float q) {
    float m = fminf(q, 1.0f);
    return (q != q) ? q : m;
}

// np.argmin update: strict < (first occurrence wins), NaN-first & sticky.
__device__ __forceinline__ bool np_argmin_better(float s, float best) {
    return (s < best) || (isnan(s) && !isnan(best));
}

// Correctly-rounded fp32 divide num/den as RN32(num * r), r = RN64(1/den).
// (no fp32/fp32 quotient is a 25-bit midpoint -> exclusion >= 2^-49 >> 2^-51.9
// rel err; den==0 -> r=+INF -> IEEE num/0.) Bit-stable since R2 (absmax pinned).
__device__ __forceinline__ float q32(float num, double r) {
    return (float)((double)num * r);
}

// argmin pairwise merge: strict < with LEFT (lower-index) preference on ties.
#define AMERGE(va, ia, vb, ib) { bool lt_ = ((vb) < (va)); \
    (va) = lt_ ? (vb) : (va); (ia) = lt_ ? (ib) : (ia); }

// async global->LDS, 16B/lane; global src is PER-LANE, LDS dest = base+lane*16.
typedef const __attribute__((address_space(1))) unsigned int* gu32p;
typedef __attribute__((address_space(3))) unsigned int* lu32p;
__device__ __forceinline__ void async_cp16(const float* g, float* l) {
    __builtin_amdgcn_global_load_lds((gu32p)(const void*)g, (lu32p)(void*)l, 16, 0, 0);
}

// FUSED, 512 blocks x 512 thr (2/CU, balanced). R17 structure + D-hoist:
// D (thread-redundant sequential sum) computed ONCE per column by a
// designated thread (same values, same order -> bit-identical), published
// via LDS; all threads drop the per-iteration D add (~11% of fast-loop issue).
#define XCH 8
#define XNC (BDIM / XCH)   // 64
__global__ __launch_bounds__(512) void rel_fused_kernel(const float* __restrict__ x,
                                                        const float* __restrict__ w,
                                                        const float* __restrict__ t,
                                                        float* __restrict__ relx,
                                                        float* __restrict__ out,
                                                        int* __restrict__ gflag) {
    __shared__ __align__(16) char lds[49152];
    const int tid = threadIdx.x;             // 0..511
    const int bid = blockIdx.x;

    if (bid < 256) {
        // ---------------- relx role (i = bid) ----------------
        float (*tbuf)[2][XCH * 64] = (float (*)[2][XCH * 64])lds;  // 32 KB
        XT* xtab = (XT*)(lds + 32768);                             // 8 KB
        float* dshare = (float*)(lds + 40960);                     // 4 B
        float* zflags = (float*)lds;         // reuse tbuf[0] pre-stream
        const int i = bid;                   // 0..255
        const int l = tid & 63, wv = tid >> 6;   // 8 waves
        const int colbase = wv * 64;         // wave's 64-col window

        bool myz;
        {   // build x-table: one strided gather + one fp64 divide per thread
            float xv  = x[(size_t)tid * IDIM + i];
            float xc  = __fsub_rn(1.0f, xv);     // x_comp
            float den = __fsub_rn(1.0f, xc);     // NOT simply xv (rounding!)
            XT e; e.r = 1.0 / (double)den; e.c = xc; e.raw = xv;
            xtab[tid] = e;                       // den==0 -> r=+INF (IEEE)
            myz = (den == 0.0f);
        }
        if (l == 0) zflags[wv] = __any(myz) ? 1.0f : 0.0f;
        __syncthreads();                     // xtab + zflags visible
        float zf = 0.0f;
        #pragma unroll
        for (int u = 0; u < 8; ++u) zf += zflags[u];
        const bool anyz = (zf != 0.0f);
        if (anyz && tid == 0) atomicOr(gflag, 1);   // device-scope, for outx
        __syncthreads();                     // flag reads done before cp16 lands

        asm volatile("s_waitcnt vmcnt(0)" ::: "memory");  // clean count
        #pragma unroll
        for (int rr = 0; rr < 2; ++rr) {     // issue chunk 0 (2 ops/wave)
            size_t row = (size_t)(rr * 4 + (l >> 4));
            async_cp16(t + row * ODIM + colbase + (l & 15) * 4,
                       &tbuf[wv][0][rr * 256 + l * 4]);
        }

        // D-hoist: thread 0 computes the (thread-identical) sequential D sum
        // once; chain latency hides under the streaming loop / co-resident block.
        if (!anyz && tid == 0) {
            float Ds = 0.0f;
            for (int b = 0; b < BDIM; ++b) Ds = __fadd_rn(Ds, xtab[b].c);
            *dshare = Ds;
        }

        float S = 0.0f, D = 0.0f;
        for (int c = 0; c < XNC; ++c) {
            if (c + 1 < XNC) {               // issue c+1 into the other buffer
                #pragma unroll
                for (int rr = 0; rr < 2; ++rr) {
                    size_t row = (size_t)((c + 1) * XCH + rr * 4 + (l >> 4));
                    async_cp16(t + row * ODIM + colbase + (l & 15) * 4,
                               &tbuf[wv][(c + 1) & 1][rr * 256 + l * 4]);
                }
                asm volatile("s_waitcnt vmcnt(2)" ::: "memory");  // c landed
            } else {
                asm volatile("s_waitcnt vmcnt(0)" ::: "memory");
            }
            const float* tb = &tbuf[wv][c & 1][0];
            if (!anyz) {                     // FAST: bit-identical, no D add
                #pragma unroll
                for (int u = 0; u < XCH; ++u) {
                    float tv = tb[u * 64 + l];
                    XT e = xtab[c * XCH + u];        // uniform broadcast b128
                    float tc  = __fsub_rn(1.0f, tv);
                    float num = __fsub_rn(tc, e.c);
                    float q   = fminf(q32(num, e.r), 1.0f);
                    S = __fadd_rn(S, q);             // exact sequential order
                }
            } else {                         // SLOW: exact IEEE/NaN semantics
                #pragma unroll
                for (int u = 0; u < XCH; ++u) {
                    float tv = tb[u * 64 + l];
                    XT e = xtab[c * XCH + u];
                    float tc  = __fsub_rn(1.0f, tv);
                    float num = __fsub_rn(tc, e.c);
                    float q   = np_min1(q32(num, e.r));
                    S = __fadd_rn(S, q);
                    D = __fadd_rn(D, e.c);           // inline D (cold path)
                }
            }
            asm volatile("" ::: "memory");
        }
        if (!anyz) {                         // block-uniform branch -> legal
            __syncthreads();                 // dshare visible
            D = *dshare;
        }
        relx[(size_t)i * ODIM + tid] = __fsub_rn(1.0f, __fdiv_rn(S, D));
    } else {
        // ------------ relw + ind_w + chosen_w for o-PAIR ------------
        XT*    wtab0  = (XT*)lds;            // 4 KB (256 entries)
        XT*    wtab1  = (XT*)(lds + 4096);   // 4 KB
        float* zflags = (float*)(lds + 8192);// 8 wave-flags (32 B)
        float* dsh    = (float*)(lds + 8192 + 32);  // 2 floats
        const int p  = bid - 256;            // 0..255
        const int o0 = 2 * p, o1 = 2 * p + 1;
        const int b  = tid;                  // 0..511
        const int l = tid & 63, wv = tid >> 6;   // 8 waves

        bool myz;
        {   // build: tid<256 -> wtab0[tid] (col o0); else wtab1[tid-256] (o1)
            int ii = tid & 255;
            int oo = (tid < 256) ? o0 : o1;
            float wvv = w[(size_t)ii * ODIM + oo];  // strided gather, once
            float wc  = __fsub_rn(1.0f, wvv);       // w_comp
            float den = __fsub_rn(1.0f, wc);
            XT e; e.r = 1.0 / (double)den; e.c = wc; e.raw = wvv;
            if (tid < 256) wtab0[ii] = e; else wtab1[ii] = e;
            myz = (den == 0.0f);
        }
        if (l == 0) zflags[wv] = __any(myz) ? 1.0f : 0.0f;
        // one aligned float2 covers t[b][o0] and t[b][o1]
        const float2 tv2 = *(const float2*)&t[(size_t)b * ODIM + o0];
        float tc0 = __fsub_rn(1.0f, tv2.x);
        float tc1 = __fsub_rn(1.0f, tv2.y);
        __syncthreads();
        float zf = 0.0f;
        #pragma unroll
        for (int u = 0; u < 8; ++u) zf += zflags[u];
        const bool anyz = (zf != 0.0f);      // zero in either column -> slow

        if (!anyz) {                         // FAST paths, D hoisted
            // designated D-chains (identical order to the old per-thread sums)
            if (tid == 0) {
                float Ds = 0.0f;
                for (int i = 0; i < IDIM; ++i) Ds = __fadd_rn(Ds, wtab0[i].c);
                dsh[0] = Ds;
            } else if (tid == 64) {
                float Ds = 0.0f;
                for (int i = 0; i < IDIM; ++i) Ds = __fadd_rn(Ds, wtab1[i].c);
                dsh[1] = Ds;
            }
            // ---- S sums (no D add) ----
            float S0 = 0.0f, S1 = 0.0f;
            #pragma unroll 8
            for (int i = 0; i < IDIM; ++i) {
                XT e = wtab0[i];             // uniform broadcast b128
                float num = __fsub_rn(tc0, e.c);
                float q   = fminf(q32(num, e.r), 1.0f);
                S0 = __fadd_rn(S0, q);
            }
            #pragma unroll 8
            for (int i = 0; i < IDIM; ++i) {
                XT e = wtab1[i];
                float num = __fsub_rn(tc1, e.c);
                float q   = fminf(q32(num, e.r), 1.0f);
                S1 = __fadd_rn(S1, q);
            }
            __syncthreads();                 // dsh visible (block-uniform path)
            float rw = __fsub_rn(1.0f, __fdiv_rn(S0, dsh[0]));
            float best = (float)INFINITY; int iw = 0;
            #pragma unroll 16
            for (int i = 0; i < IDIM; ++i) {
                float a = wtab0[i].raw;      // uniform broadcast b32
                float s = __fsub_rn(__fadd_rn(a, rw), __fmul_rn(a, rw));
                bool lt = (s < best);        // strict < : first occurrence
                best = lt ? s : best; iw = lt ? i : iw;
            }
            out[(size_t)BDIM * ODIM + (size_t)b * ODIM + o0] =
                fmaxf(x[(size_t)b * IDIM + iw], wtab0[iw].raw);
            rw = __fsub_rn(1.0f, __fdiv_rn(S1, dsh[1]));
            best = (float)INFINITY; iw = 0;
            #pragma unroll 16
            for (int i = 0; i < IDIM; ++i) {
                float a = wtab1[i].raw;
                float s = __fsub_rn(__fadd_rn(a, rw), __fmul_rn(a, rw));
                bool lt = (s < best);
                best = lt ? s : best; iw = lt ? i : iw;
            }
            out[(size_t)BDIM * ODIM + (size_t)b * ODIM + o1] =
                fmaxf(x[(size_t)b * IDIM + iw], wtab1[iw].raw);
        } else {                             // SLOW: exact IEEE/NaN semantics
            float S = 0.0f, D = 0.0f;
            #pragma unroll 8
            for (int i = 0; i < IDIM; ++i) {
                XT e = wtab0[i];
                float num = __fsub_rn(tc0, e.c);
                float q   = np_min1(q32(num, e.r));
                S = __fadd_rn(S, q);
                D = __fadd_rn(D, e.c);
            }
            float rw = __fsub_rn(1.0f, __fdiv_rn(S, D));
            float best = (float)INFINITY; int iw = 0;
            #pragma unroll 8
            for (int i = 0; i < IDIM; ++i) {
                float a = wtab0[i].raw;
                float s = __fsub_rn(__fadd_rn(a, rw), __fmul_rn(a, rw));
                if (np_argmin_better(s, best)) { best = s; iw = i; }
            }
            out[(size_t)BDIM * ODIM + (size_t)b * ODIM + o0] =
                fmaxf(x[(size_t)b * IDIM + iw], wtab0[iw].raw);
            S = 0.0f; D = 0.0f;
            #pragma unroll 8
            for (int i = 0; i < IDIM; ++i) {
                XT e = wtab1[i];
                float num = __fsub_rn(tc1, e.c);
                float q   = np_min1(q32(num, e.r));
                S = __fadd_rn(S, q);
                D = __fadd_rn(D, e.c);
            }
            rw = __fsub_rn(1.0f, __fdiv_rn(S, D));
            best = (float)INFINITY; iw = 0;
            #pragma unroll 8
            for (int i = 0; i < IDIM; ++i) {
                float a = wtab1[i].raw;
                float s = __fsub_rn(__fadd_rn(a, rw), __fmul_rn(a, rw));
                if (np_argmin_better(s, best)) { best = s; iw = i; }
            }
            out[(size_t)BDIM * ODIM + (size_t)b * ODIM + o1] =
                fmaxf(x[(size_t)b * IDIM + iw], wtab1[iw].raw);
        }
    }
}

// K2 (R14/R16 verbatim): sx argmin + chosen_x, 2048 blocks x 256 thr (8/CU).
// Block = (b, 128-o window). Waves 0,1: i in [0,128); waves 2,3: [128,256);
// (val,idx) merged via LDS — exact (lexicographic-min associativity).
#define OCH 8
#define ONX 16   // 128 / OCH
__global__ __launch_bounds__(256) void outx_kernel(const float* __restrict__ x,
                                                   const float* __restrict__ w,
                                                   const float* __restrict__ relx,
                                                   const int* __restrict__ gflag,
                                                   float* __restrict__ out) {
    __shared__ float rbuf[4][2][OCH * 64];   // 16 KB (per-wave private)
    __shared__ float xrow[IDIM];             // 1 KB
    __shared__ float mval[128];
    __shared__ int   midx[128];
    const int tid = threadIdx.x;             // 0..255
    const int b   = blockIdx.x >> 2;         // 0..511
    const int obase = (blockIdx.x & 3) * 128;
    const int l = tid & 63, wv = tid >> 6;   // 4 waves
    const int ow    = obase + (wv & 1) * 64; // wave's o-window
    const int ibase = (wv >> 1) * 128;       // wave's i-half
    const int o = ow + l;

    xrow[tid] = x[(size_t)b * IDIM + tid];   // coalesced (256 == IDIM)
    const bool anyz = (*gflag & 1) != 0;     // x had a zero -> relx may be INF/NaN
    asm volatile("s_waitcnt vmcnt(0)" ::: "memory");  // clean count
    #pragma unroll
    for (int rr = 0; rr < 2; ++rr) {         // issue chunk 0 (2 ops/wave)
        size_t row = (size_t)(ibase + rr * 4 + (l >> 4));
        async_cp16(relx + row * ODIM + ow + (l & 15) * 4,
                   &rbuf[wv][0][rr * 256 + l * 4]);
    }
    asm volatile("s_waitcnt lgkmcnt(0)" ::: "memory");  // xrow write done
    __builtin_amdgcn_s_barrier();                       // xrow visible

    float bx = (float)INFINITY; int ix = ibase;  // seed == first-occurrence
    for (int c = 0; c < ONX; ++c) {
        if (c + 1 < ONX) {                   // issue c+1 into the other buffer
            #pragma unroll
            for (int rr = 0; rr < 2; ++rr) {
                size_t row = (size_t)(ibase + (c + 1) * OCH + rr * 4 + (l >> 4));
                async_cp16(relx + row * ODIM + ow + (l & 15) * 4,
                           &rbuf[wv][(c + 1) & 1][rr * 256 + l * 4]);
            }
            asm volatile("s_waitcnt vmcnt(2)" ::: "memory");  // c landed
        } else {
            asm volatile("s_waitcnt vmcnt(0)" ::: "memory");
        }
        const float* rb = &rbuf[wv][c & 1][0];
        if (!anyz) {                         // FAST: strict-< scan
            #pragma unroll
            for (int u = 0; u < OCH; ++u) {
                int ii = ibase + c * OCH + u;
                float rl = rb[u * 64 + l];   // 2-way bank (free)
                float xv = xrow[ii];         // uniform broadcast
                float s  = __fsub_rn(__fadd_rn(xv, rl), __fmul_rn(xv, rl));
                bool lt = (s < bx);
                bx = lt ? s : bx; ix = lt ? ii : ix;
            }
        } else {                             // SLOW: exact NaN-first semantics
            #pragma unroll
            for (int u = 0; u < OCH; ++u) {
                int ii = ibase + c * OCH + u;
                float rl = rb[u * 64 + l];
                float xv = xrow[ii];
                float s  = __fsub_rn(__fadd_rn(xv, rl), __fmul_rn(xv, rl));
                if (np_argmin_better(s, bx)) { bx = s; ix = ii; }
            }
        }
        asm volatile("" ::: "memory");
    }
    // cross-half merge: waves 2,3 (high i) publish; waves 0,1 (low i) consume.
    const int slot = (wv & 1) * 64 + l;
    if (wv >= 2) { mval[slot] = bx; midx[slot] = ix; }
    __syncthreads();
    if (wv < 2) {
        float v2 = mval[slot]; int i2 = midx[slot];   // i2 >= 128 > ix's range
        if (!anyz) { AMERGE(bx, ix, v2, i2); }
        else if (np_argmin_better(v2, bx)) { bx = v2; ix = i2; }
        float cx = fmaxf(xrow[ix], w[(size_t)ix * ODIM + o]);  // 1 gather
        out[(size_t)b * ODIM + o] = cx;                        // chosen_x
    }
}

extern "C" void kernel_launch(void* const* d_in, const int* in_sizes, int n_in,
                              void* d_out, int out_size, void* d_ws, size_t ws_size,
                              hipStream_t stream) {
    const float* x = (const float*)d_in[0];  // (B, I)
    const float* w = (const float*)d_in[1];  // (I, O)
    const float* t = (const float*)d_in[2];  // (B, O)
    float* out = (float*)d_out;              // [chosen_x | chosen_w]

    float* relx = (float*)d_ws;              // I*O*4 = 512 KB
    int* gflag  = (int*)((char*)d_ws + (size_t)IDIM * ODIM * 4);

    hipMemsetAsync(gflag, 0, 4, stream);
    hipLaunchKernelGGL(rel_fused_kernel, dim3(512), dim3(512), 0, stream,
                       x, w, t, relx, out, gflag);
    hipLaunchKernelGGL(outx_kernel, dim3(2048), dim3(256), 0, stream,
                       x, w, relx, gflag, out);
}

// Round 19
// 63.605 us; speedup vs baseline: 1.0210x; 1.0210x over previous
//
#include <hip/hip_runtime.h>
#include <math.h>

#define BDIM 512
#define IDIM 256
#define ODIM 512

// 16B table entry: correctly-rounded fp64 reciprocal of den, comp, raw value.
struct __align__(16) XT { double r; float c; float raw; };

// jnp.minimum(q, 1.0): NaN-propagating min with 1.0 (slow/general path)
__device__ __forceinline__ float np_min1(float q) {
    float m = fminf(q, 1.0f);
    return (q != q) ? q : m;
}

// np.argmin update: strict < (first occurrence wins), NaN-first & sticky.
__device__ __forceinline__ bool np_argmin_better(float s, float best) {
    return (s < best) || (isnan(s) && !isnan(best));
}

// Correctly-rounded fp32 divide num/den as RN32(num * r), r = RN64(1/den).
// (no fp32/fp32 quotient is a 25-bit midpoint -> exclusion >= 2^-49 >> 2^-51.9
// rel err; den==0 -> r=+INF -> IEEE num/0.) Bit-stable since R2 (absmax pinned).
__device__ __forceinline__ float q32(float num, double r) {
    return (float)((double)num * r);
}

// argmin pairwise merge: strict < with LEFT (lower-index) preference on ties.
#define AMERGE(va, ia, vb, ib) { bool lt_ = ((vb) < (va)); \
    (va) = lt_ ? (vb) : (va); (ia) = lt_ ? (ib) : (ia); }

// async global->LDS, 16B/lane; global src is PER-LANE, LDS dest = base+lane*16.
typedef const __attribute__((address_space(1))) unsigned int* gu32p;
typedef __attribute__((address_space(3))) unsigned int* lu32p;
__device__ __forceinline__ void async_cp16(const float* g, float* l) {
    __builtin_amdgcn_global_load_lds((gu32p)(const void*)g, (lu32p)(void*)l, 16, 0, 0);
}

// FUSED, 512 blocks x 512 thr (2/CU, balanced):
//   bid <  256: relx role, i = bid            (R12/R16 inner loops verbatim)
//   bid >= 256: relw+ind_w+chosen_w for o-PAIR (o = 2p, 2p+1), p = bid-256.
// XCD round-robin gives each CU bids {j, j+256} = one relx + one relw-pair;
// both blocks have ~equal work -> no serial tail.
#define XCH 8
#define XNC (BDIM / XCH)   // 64
__global__ __launch_bounds__(512) void rel_fused_kernel(const float* __restrict__ x,
                                                        const float* __restrict__ w,
                                                        const float* __restrict__ t,
                                                        float* __restrict__ relx,
                                                        float* __restrict__ out,
                                                        int* __restrict__ gflag) {
    __shared__ __align__(16) char lds[49152];
    const int tid = threadIdx.x;             // 0..511
    const int bid = blockIdx.x;

    if (bid < 256) {
        // ---------------- relx role (i = bid) ----------------
        float (*tbuf)[2][XCH * 64] = (float (*)[2][XCH * 64])lds;  // 32 KB
        XT* xtab = (XT*)(lds + 32768);                             // 8 KB
        float* zflags = (float*)lds;         // reuse tbuf[0] pre-stream
        const int i = bid;                   // 0..255
        const int l = tid & 63, wv = tid >> 6;   // 8 waves
        const int colbase = wv * 64;         // wave's 64-col window

        bool myz;
        {   // build x-table: one strided gather + one fp64 divide per thread
            float xv  = x[(size_t)tid * IDIM + i];
            float xc  = __fsub_rn(1.0f, xv);     // x_comp
            float den = __fsub_rn(1.0f, xc);     // NOT simply xv (rounding!)
            XT e; e.r = 1.0 / (double)den; e.c = xc; e.raw = xv;
            xtab[tid] = e;                       // den==0 -> r=+INF (IEEE)
            myz = (den == 0.0f);
        }
        if (l == 0) zflags[wv] = __any(myz) ? 1.0f : 0.0f;
        __syncthreads();                     // xtab + zflags visible
        float zf = 0.0f;
        #pragma unroll
        for (int u = 0; u < 8; ++u) zf += zflags[u];
        const bool anyz = (zf != 0.0f);
        if (anyz && tid == 0) atomicOr(gflag, 1);   // device-scope, for outx
        __syncthreads();                     // flag reads done before cp16 lands

        asm volatile("s_waitcnt vmcnt(0)" ::: "memory");  // clean count
        #pragma unroll
        for (int rr = 0; rr < 2; ++rr) {     // issue chunk 0 (2 ops/wave)
            size_t row = (size_t)(rr * 4 + (l >> 4));
            async_cp16(t + row * ODIM + colbase + (l & 15) * 4,
                       &tbuf[wv][0][rr * 256 + l * 4]);
        }

        float S = 0.0f, D = 0.0f;
        for (int c = 0; c < XNC; ++c) {
            if (c + 1 < XNC) {               // issue c+1 into the other buffer
                #pragma unroll
                for (int rr = 0; rr < 2; ++rr) {
                    size_t row = (size_t)((c + 1) * XCH + rr * 4 + (l >> 4));
                    async_cp16(t + row * ODIM + colbase + (l & 15) * 4,
                               &tbuf[wv][(c + 1) & 1][rr * 256 + l * 4]);
                }
                asm volatile("s_waitcnt vmcnt(2)" ::: "memory");  // c landed
            } else {
                asm volatile("s_waitcnt vmcnt(0)" ::: "memory");
            }
            const float* tb = &tbuf[wv][c & 1][0];
            if (!anyz) {                     // FAST: bit-identical
                #pragma unroll
                for (int u = 0; u < XCH; ++u) {
                    float tv = tb[u * 64 + l];
                    XT e = xtab[c * XCH + u];        // uniform broadcast b128
                    float tc  = __fsub_rn(1.0f, tv);
                    float num = __fsub_rn(tc, e.c);
                    float q   = fminf(q32(num, e.r), 1.0f);
                    S = __fadd_rn(S, q);             // exact sequential order
                    D = __fadd_rn(D, e.c);
                }
            } else {                         // SLOW: exact IEEE/NaN semantics
                #pragma unroll
                for (int u = 0; u < XCH; ++u) {
                    float tv = tb[u * 64 + l];
                    XT e = xtab[c * XCH + u];
                    float tc  = __fsub_rn(1.0f, tv);
                    float num = __fsub_rn(tc, e.c);
                    float q   = np_min1(q32(num, e.r));
                    S = __fadd_rn(S, q);
                    D = __fadd_rn(D, e.c);
                }
            }
            asm volatile("" ::: "memory");
        }
        relx[(size_t)i * ODIM + tid] = __fsub_rn(1.0f, __fdiv_rn(S, D));
    } else {
        // ------------ relw + ind_w + chosen_w for o-PAIR ------------
        XT*    wtab0  = (XT*)lds;            // 4 KB (256 entries)
        XT*    wtab1  = (XT*)(lds + 4096);   // 4 KB
        float* zflags = (float*)(lds + 8192);// 8 wave-flags
        const int p  = bid - 256;            // 0..255
        const int o0 = 2 * p, o1 = 2 * p + 1;
        const int b  = tid;                  // 0..511
        const int l = tid & 63, wv = tid >> 6;   // 8 waves

        bool myz;
        {   // build: tid<256 -> wtab0[tid] (col o0); else wtab1[tid-256] (o1)
            int ii = tid & 255;
            int oo = (tid < 256) ? o0 : o1;
            float wvv = w[(size_t)ii * ODIM + oo];  // strided gather, once
            float wc  = __fsub_rn(1.0f, wvv);       // w_comp
            float den = __fsub_rn(1.0f, wc);
            XT e; e.r = 1.0 / (double)den; e.c = wc; e.raw = wvv;
            if (tid < 256) wtab0[ii] = e; else wtab1[ii] = e;
            myz = (den == 0.0f);
        }
        if (l == 0) zflags[wv] = __any(myz) ? 1.0f : 0.0f;
        // one aligned float2 covers t[b][o0] and t[b][o1]
        const float2 tv2 = *(const float2*)&t[(size_t)b * ODIM + o0];
        float tc0 = __fsub_rn(1.0f, tv2.x);
        float tc1 = __fsub_rn(1.0f, tv2.y);
        __syncthreads();
        float zf = 0.0f;
        #pragma unroll
        for (int u = 0; u < 8; ++u) zf += zflags[u];
        const bool anyz = (zf != 0.0f);      // zero in either column -> slow

        if (!anyz) {                         // FAST paths (R16 loops verbatim)
            // ---- o0 ----
            float S = 0.0f, D = 0.0f;
            #pragma unroll 8
            for (int i = 0; i < IDIM; ++i) {
                XT e = wtab0[i];             // uniform broadcast b128
                float num = __fsub_rn(tc0, e.c);
                float q   = fminf(q32(num, e.r), 1.0f);
                S = __fadd_rn(S, q);
                D = __fadd_rn(D, e.c);
            }
            float rw = __fsub_rn(1.0f, __fdiv_rn(S, D));
            float best = (float)INFINITY; int iw = 0;
            #pragma unroll 16
            for (int i = 0; i < IDIM; ++i) {
                float a = wtab0[i].raw;      // uniform broadcast b32
                float s = __fsub_rn(__fadd_rn(a, rw), __fmul_rn(a, rw));
                bool lt = (s < best);        // strict < : first occurrence
                best = lt ? s : best; iw = lt ? i : iw;
            }
            out[(size_t)BDIM * ODIM + (size_t)b * ODIM + o0] =
                fmaxf(x[(size_t)b * IDIM + iw], wtab0[iw].raw);
            // ---- o1 ----
            S = 0.0f; D = 0.0f;
            #pragma unroll 8
            for (int i = 0; i < IDIM; ++i) {
                XT e = wtab1[i];
                float num = __fsub_rn(tc1, e.c);
                float q   = fminf(q32(num, e.r), 1.0f);
                S = __fadd_rn(S, q);
                D = __fadd_rn(D, e.c);
            }
            rw = __fsub_rn(1.0f, __fdiv_rn(S, D));
            best = (float)INFINITY; iw = 0;
            #pragma unroll 16
            for (int i = 0; i < IDIM; ++i) {
                float a = wtab1[i].raw;
                float s = __fsub_rn(__fadd_rn(a, rw), __fmul_rn(a, rw));
                bool lt = (s < best);
                best = lt ? s : best; iw = lt ? i : iw;
            }
            out[(size_t)BDIM * ODIM + (size_t)b * ODIM + o1] =
                fmaxf(x[(size_t)b * IDIM + iw], wtab1[iw].raw);
        } else {                             // SLOW: exact IEEE/NaN semantics
            float S = 0.0f, D = 0.0f;
            #pragma unroll 8
            for (int i = 0; i < IDIM; ++i) {
                XT e = wtab0[i];
                float num = __fsub_rn(tc0, e.c);
                float q   = np_min1(q32(num, e.r));
                S = __fadd_rn(S, q);
                D = __fadd_rn(D, e.c);
            }
            float rw = __fsub_rn(1.0f, __fdiv_rn(S, D));
            float best = (float)INFINITY; int iw = 0;
            #pragma unroll 8
            for (int i = 0; i < IDIM; ++i) {
                float a = wtab0[i].raw;
                float s = __fsub_rn(__fadd_rn(a, rw), __fmul_rn(a, rw));
                if (np_argmin_better(s, best)) { best = s; iw = i; }
            }
            out[(size_t)BDIM * ODIM + (size_t)b * ODIM + o0] =
                fmaxf(x[(size_t)b * IDIM + iw], wtab0[iw].raw);
            S = 0.0f; D = 0.0f;
            #pragma unroll 8
            for (int i = 0; i < IDIM; ++i) {
                XT e = wtab1[i];
                float num = __fsub_rn(tc1, e.c);
                float q   = np_min1(q32(num, e.r));
                S = __fadd_rn(S, q);
                D = __fadd_rn(D, e.c);
            }
            rw = __fsub_rn(1.0f, __fdiv_rn(S, D));
            best = (float)INFINITY; iw = 0;
            #pragma unroll 8
            for (int i = 0; i < IDIM; ++i) {
                float a = wtab1[i].raw;
                float s = __fsub_rn(__fadd_rn(a, rw), __fmul_rn(a, rw));
                if (np_argmin_better(s, best)) { best = s; iw = i; }
            }
            out[(size_t)BDIM * ODIM + (size_t)b * ODIM + o1] =
                fmaxf(x[(size_t)b * IDIM + iw], wtab1[iw].raw);
        }
    }
}

// K2 (R14/R16 verbatim): sx argmin + chosen_x, 2048 blocks x 256 thr (8/CU).
// Block = (b, 128-o window). Waves 0,1: i in [0,128); waves 2,3: [128,256);
// (val,idx) merged via LDS — exact (lexicographic-min associativity).
#define OCH 8
#define ONX 16   // 128 / OCH
__global__ __launch_bounds__(256) void outx_kernel(const float* __restrict__ x,
                                                   const float* __restrict__ w,
                                                   const float* __restrict__ relx,
                                                   const int* __restrict__ gflag,
                                                   float* __restrict__ out) {
    __shared__ float rbuf[4][2][OCH * 64];   // 16 KB (per-wave private)
    __shared__ float xrow[IDIM];             // 1 KB
    __shared__ float mval[128];
    __shared__ int   midx[128];
    const int tid = threadIdx.x;             // 0..255
    const int b   = blockIdx.x >> 2;         // 0..511
    const int obase = (blockIdx.x & 3) * 128;
    const int l = tid & 63, wv = tid >> 6;   // 4 waves
    const int ow    = obase + (wv & 1) * 64; // wave's o-window
    const int ibase = (wv >> 1) * 128;       // wave's i-half
    const int o = ow + l;

    xrow[tid] = x[(size_t)b * IDIM + tid];   // coalesced (256 == IDIM)
    const bool anyz = (*gflag & 1) != 0;     // x had a zero -> relx may be INF/NaN
    asm volatile("s_waitcnt vmcnt(0)" ::: "memory");  // clean count
    #pragma unroll
    for (int rr = 0; rr < 2; ++rr) {         // issue chunk 0 (2 ops/wave)
        size_t row = (size_t)(ibase + rr * 4 + (l >> 4));
        async_cp16(relx + row * ODIM + ow + (l & 15) * 4,
                   &rbuf[wv][0][rr * 256 + l * 4]);
    }
    asm volatile("s_waitcnt lgkmcnt(0)" ::: "memory");  // xrow write done
    __builtin_amdgcn_s_barrier();                       // xrow visible

    float bx = (float)INFINITY; int ix = ibase;  // seed == first-occurrence
    for (int c = 0; c < ONX; ++c) {
        if (c + 1 < ONX) {                   // issue c+1 into the other buffer
            #pragma unroll
            for (int rr = 0; rr < 2; ++rr) {
                size_t row = (size_t)(ibase + (c + 1) * OCH + rr * 4 + (l >> 4));
                async_cp16(relx + row * ODIM + ow + (l & 15) * 4,
                           &rbuf[wv][(c + 1) & 1][rr * 256 + l * 4]);
            }
            asm volatile("s_waitcnt vmcnt(2)" ::: "memory");  // c landed
        } else {
            asm volatile("s_waitcnt vmcnt(0)" ::: "memory");
        }
        const float* rb = &rbuf[wv][c & 1][0];
        if (!anyz) {                         // FAST: strict-< scan
            #pragma unroll
            for (int u = 0; u < OCH; ++u) {
                int ii = ibase + c * OCH + u;
                float rl = rb[u * 64 + l];   // 2-way bank (free)
                float xv = xrow[ii];         // uniform broadcast
                float s  = __fsub_rn(__fadd_rn(xv, rl), __fmul_rn(xv, rl));
                bool lt = (s < bx);
                bx = lt ? s : bx; ix = lt ? ii : ix;
            }
        } else {                             // SLOW: exact NaN-first semantics
            #pragma unroll
            for (int u = 0; u < OCH; ++u) {
                int ii = ibase + c * OCH + u;
                float rl = rb[u * 64 + l];
                float xv = xrow[ii];
                float s  = __fsub_rn(__fadd_rn(xv, rl), __fmul_rn(xv, rl));
                if (np_argmin_better(s, bx)) { bx = s; ix = ii; }
            }
        }
        asm volatile("" ::: "memory");
    }
    // cross-half merge: waves 2,3 (high i) publish; waves 0,1 (low i) consume.
    const int slot = (wv & 1) * 64 + l;
    if (wv >= 2) { mval[slot] = bx; midx[slot] = ix; }
    __syncthreads();
    if (wv < 2) {
        float v2 = mval[slot]; int i2 = midx[slot];   // i2 >= 128 > ix's range
        if (!anyz) { AMERGE(bx, ix, v2, i2); }
        else if (np_argmin_better(v2, bx)) { bx = v2; ix = i2; }
        float cx = fmaxf(xrow[ix], w[(size_t)ix * ODIM + o]);  // 1 gather
        out[(size_t)b * ODIM + o] = cx;                        // chosen_x
    }
}

extern "C" void kernel_launch(void* const* d_in, const int* in_sizes, int n_in,
                              void* d_out, int out_size, void* d_ws, size_t ws_size,
                              hipStream_t stream) {
    const float* x = (const float*)d_in[0];  // (B, I)
    const float* w = (const float*)d_in[1];  // (I, O)
    const float* t = (const float*)d_in[2];  // (B, O)
    float* out = (float*)d_out;              // [chosen_x | chosen_w]

    float* relx = (float*)d_ws;              // I*O*4 = 512 KB
    int* gflag  = (int*)((char*)d_ws + (size_t)IDIM * ODIM * 4);

    hipMemsetAsync(gflag, 0, 4, stream);
    hipLaunchKernelGGL(rel_fused_kernel, dim3(512), dim3(512), 0, stream,
                       x, w, t, relx, out, gflag);
    hipLaunchKernelGGL(outx_kernel, dim3(2048), dim3(256), 0, stream,
                       x, w, relx, gflag, out);
}